// Round 2
// 69.345 us; speedup vs baseline: 1.0676x; 1.0676x over previous
//
#include <hip/hip_runtime.h>
#include <math.h>

// DotDetectionLoss on MI355X — SINGLE kernel node (finalize folded in via a
// poison-agnostic last-block pattern; only assumption: ws poison != MAGIC,
// same assumption the verified wflags trick already makes).
// pred: (16, 4096, 4) f32 = [cls, x, y, conf]; gt: (16, 1024, 3) f32 = [cls, x, y]
// out: float[2] = {obj_loss, reg_loss}
//
// Math: sigmoid(2.5-d) monotone in d => masked argmax(score) == argmin(d^2) among
// {class match, d2 <= 6.25}; score>=0.5 <=> d2 <= 6.25 (+1e-12 is sub-ulp).
// Spatial hash 64x64 cells (8px): r=2.5 disc spans <=2x2 cells (+0.01 window
// guard; superset safe — exact d2<=6.25 decides). Tie-break
// (d2<bd)||(d2==bd&&p<bp) == JAX argmax first-index (order-independent).
// Obj split: bce(x,1)=bce(x,0)-x => obj = [sum_p bce0(x_p) - sum_correct x_p]/BP.
// Class folded into SIGN BIT of stored x (inputs are >=0; fabsf is exact), so
// the match phase is 100% LDS-resident: no random global loads on the chain.
// Match uses ALL 1024 threads: 4 threads/target, one per window cell, then a
// 2-step shfl_xor lexicographic (d2,p) reduce within each 4-group.
//
// Finalize ordering (release/acquire, device-scope atomics):
//   publisher: partials exch -> __threadfence -> done exch -> s_waitcnt vmcnt(0)
//   (waitcnt guarantees OWN done exch is globally performed before this wave
//   samples the other 63 flags, so the globally-last publisher always sees
//   all-MAGIC => out is always written; fguard exch picks a unique finalizer.)

#define NB 16
#define NP 4096
#define NT 1024
#define MAGIC 0x5CA1AB1Eu

// ws layout (bytes): wflags u32[NB*NP] (256 KB) | partials f32[128] | done u32[64] | fguard u32
#define O_WFLAGS 0
#define O_PART   (NB * NP * 4)
#define O_DONE   (O_PART + 128 * 4)
#define O_FGUARD (O_DONE + 64 * 4)

__global__ __launch_bounds__(1024) void k_all(
    const float4* __restrict__ pred, const float* __restrict__ gt,
    unsigned* __restrict__ wflags, float* __restrict__ partials,
    unsigned* __restrict__ done, unsigned* __restrict__ fguard,
    float* __restrict__ out)
{
    const int bid = blockIdx.x;
    const int b = bid >> 2, q = bid & 3;      // 4 blocks per image
    const int tid = threadIdx.x, lane = tid & 63, wave = tid >> 6;

    __shared__ unsigned short scnt[4096];     // cell counts -> cursors -> ENDs
    __shared__ unsigned short sbins[4096];    // pred ids grouped by cell
    __shared__ float2 spxy[4096];             // binned pred (sign(cls)|x, y); first 12KB doubles as gt staging
    __shared__ float2 sxy[NT];                // gt (sign(cls)|x, y)
    __shared__ unsigned short slist[256];     // owned correct preds
    __shared__ unsigned scount;
    __shared__ unsigned wsum[16];
    __shared__ float pc[2];                   // obj partial, score partial

    const float4* pb = pred + (size_t)b * NP;
    const float*  gb = gt + (size_t)b * NT * 3;
    float* sraw = (float*)spxy;               // gt staging (12 KB of 32 KB; consumed before fill)

    // ---- init LDS + coalesced gt stage ----
    ((unsigned*)scnt)[tid] = 0u;
    ((unsigned*)scnt)[tid + 1024] = 0u;
    if (tid == 0) scount = 0u;
    if (tid < 2) pc[tid] = 0.0f;
    sraw[tid]        = gb[tid];
    sraw[tid + 1024] = gb[tid + 1024];
    sraw[tid + 2048] = gb[tid + 2048];
    __syncthreads();

    // ---- recombine gt (cls -> sign of x) ----
    {
        float c = sraw[3 * tid], x = sraw[3 * tid + 1], y = sraw[3 * tid + 2];
        sxy[tid] = make_float2(c != 0.0f ? -x : x, y);
    }

    // ---- count (packed u16 LDS atomics; halfwords <=4096, no carry) + BCE
    //      baseline on this block's owned quarter (k==q element, no extra load) ----
    float4 prv[4];
    int cellc[4];
    float lb = 0.0f;
    #pragma unroll
    for (int k = 0; k < 4; k++) {
        float4 pr = pb[tid + 1024 * k];
        prv[k] = pr;
        int cell = (int)(pr.y * 0.125f) + ((int)(pr.z * 0.125f) << 6);
        cellc[k] = cell;
        atomicAdd((unsigned*)scnt + (cell >> 1), (cell & 1) ? 0x10000u : 1u);
        if (k == q) {
            float x = pr.w;
            lb = fmaxf(x, 0.0f) + log1pf(expf(-fabsf(x)));   // bce(x, y=0)
        }
    }
    for (int off = 32; off; off >>= 1) lb += __shfl_down(lb, off, 64);
    if (lane == 0) atomicAdd(&pc[0], lb);
    __syncthreads();

    // ---- exclusive scan over 4096 cells (4 cells/thread, 16 waves) ----
    {
        int base = tid * 4;
        unsigned loc[4], s = 0;
        #pragma unroll
        for (int i = 0; i < 4; i++) { loc[i] = s; s += (unsigned)scnt[base + i]; }
        unsigned v = s;
        for (int off = 1; off < 64; off <<= 1) {
            unsigned o = __shfl_up(v, off, 64);
            if (lane >= off) v += o;
        }
        if (lane == 63) wsum[wave] = v;
        __syncthreads();
        unsigned wbase = 0;
        for (int w = 0; w < wave; w++) wbase += wsum[w];
        unsigned tbase = wbase + v - s;
        #pragma unroll
        for (int i = 0; i < 4; i++) scnt[base + i] = (unsigned short)(tbase + loc[i]);
    }
    __syncthreads();

    // ---- fill (cursor = packed atomic; post-fill scnt[c] == END of cell c);
    //      also deposit (sign-encoded x, y) so match never touches global ----
    #pragma unroll
    for (int k = 0; k < 4; k++) {
        int cell = cellc[k];
        unsigned old = atomicAdd((unsigned*)scnt + (cell >> 1), (cell & 1) ? 0x10000u : 1u);
        unsigned slot = (cell & 1) ? (old >> 16) : (old & 0xFFFFu);
        sbins[slot] = (unsigned short)(tid + 1024 * k);
        float4 pr = prv[k];
        spxy[slot] = make_float2(pr.x != 0.0f ? -pr.y : pr.y, pr.z);
    }
    __syncthreads();

    // ---- match: ALL 1024 threads, 4 threads per target (one per window cell) ----
    {
        const int t = q * 256 + (tid >> 2);
        const int j = tid & 3;
        float2 txy = sxy[t];
        const int tsign = __float_as_int(txy.x);
        const float tx = fabsf(txy.x), ty = txy.y;
        int x0 = (int)floorf((tx - 2.51f) * 0.125f); if (x0 < 0) x0 = 0;
        int x1 = (int)((tx + 2.51f) * 0.125f);       if (x1 > 63) x1 = 63;
        int y0 = (int)floorf((ty - 2.51f) * 0.125f); if (y0 < 0) y0 = 0;
        int y1 = (int)((ty + 2.51f) * 0.125f);       if (y1 > 63) y1 = 63;
        float bd = 3.0e38f; int bp = 0x7fffffff;
        const int cx = x0 + (j & 1), cy = y0 + (j >> 1);
        if (cx <= x1 && cy <= y1) {
            const int c = cx + (cy << 6);
            unsigned s0 = c ? (unsigned)scnt[c - 1] : 0u;
            unsigned s1 = (unsigned)scnt[c];
            for (unsigned k = s0; k < s1; k++) {
                float2 pxy = spxy[k];
                if (((__float_as_int(pxy.x) ^ tsign) & 0x80000000) == 0) {   // class match
                    float dx = fabsf(pxy.x) - tx, dy = pxy.y - ty;           // fabsf exact: d2 bitwise-identical
                    float d2 = fmaf(dy, dy, dx * dx);
                    int p = sbins[k];
                    if (d2 < bd || (d2 == bd && p < bp)) { bd = d2; bp = p; }
                }
            }
        }
        #pragma unroll
        for (int m = 1; m <= 2; m <<= 1) {      // lexicographic (d2,p) reduce over the 4-group
            float od = __shfl_xor(bd, m, 64);
            int   op = __shfl_xor(bp, m, 64);
            if (od < bd || (od == bd && op < bp)) { bd = od; bp = op; }
        }
        if (j == 0 && bd <= 6.25f) {
            // cross-block dedupe: first exchanger owns (poison != MAGIC), race-free
            unsigned old = atomicExch(&wflags[b * NP + bp], MAGIC);
            if (old != MAGIC)
                slist[atomicAdd(&scount, 1u)] = (unsigned short)bp;
        }
    }
    __syncthreads();

    // ---- reg + obj correction: one wave per owned correct pred (16 waves) ----
    {
        unsigned n = scount;
        float lc = 0.0f, ls = 0.0f;
        for (unsigned e = (unsigned)wave; e < n; e += 16) {
            int p = slist[e];
            float4 pr = pb[p];
            float md = 1.0e30f;
            #pragma unroll 4
            for (int t = lane; t < NT; t += 64) {
                float2 xy = sxy[t];
                float dx = pr.y - fabsf(xy.x), dy = pr.z - xy.y;
                md = fminf(md, fmaf(dy, dy, dx * dx));
            }
            for (int off = 32; off; off >>= 1)
                md = fminf(md, __shfl_down(md, off, 64));
            if (lane == 0) {
                float dd = sqrtf(md + 1e-12f);
                ls += 1.0f / (1.0f + expf(dd - 2.5f));
                lc += pr.w;                   // bce(x,1) = bce(x,0) - x
            }
        }
        if (lane == 0 && (lc != 0.0f || ls != 0.0f)) {
            atomicAdd(&pc[0], -lc);           // obj partial -= correction
            atomicAdd(&pc[1], ls);
        }
    }
    __syncthreads();

    // ---- publish (device-scope atomics: coherent across XCD L2s) + last-block
    //      finalize. Release: partials -> fence -> done[bid]=MAGIC. The
    //      s_waitcnt vmcnt(0) below is wave-wide: it guarantees lane 0's done
    //      exch is globally performed BEFORE any lane of wave 0 issues its
    //      flag read, so the globally-last publisher must observe all 64
    //      flags == MAGIC (own flag substituted locally) => out always
    //      written. fguard exch (poison != MAGIC) picks a unique finalizer;
    //      its returned value is consumed, so the wave waits before reading
    //      partials (plus acquire threadfence). Summation order replicates
    //      the old k_fin exactly => bitwise-same out. ----
    if (tid == 0) {
        atomicExch(&partials[bid], pc[0]);         // obj partial
        atomicExch(&partials[64 + bid], pc[1]);    // score partial
        __threadfence();
        atomicExch(&done[bid], MAGIC);
    }
    if (wave == 0) {
        asm volatile("s_waitcnt vmcnt(0)" ::: "memory");   // own exch performed
        unsigned f = (lane == bid) ? MAGIC : atomicAdd(&done[lane], 0u);
        if (__ballot(f == MAGIC) == ~0ull) {
            int win = 0;
            if (lane == 0) win = (atomicExch(fguard, MAGIC) != MAGIC) ? 1 : 0;
            if (__shfl(win, 0, 64)) {
                __threadfence();
                // identical summation order to the old k_fin => bitwise-same out
                float v0 = atomicAdd(&partials[lane], 0.0f);
                for (int off = 32; off; off >>= 1) v0 += __shfl_down(v0, off, 64);
                float v1 = atomicAdd(&partials[64 + lane], 0.0f);
                for (int off = 32; off; off >>= 1) v1 += __shfl_down(v1, off, 64);
                if (lane == 0) {
                    const float inv = 1.0f / (float)(NB * NP);
                    out[0] = v0 * inv;             // obj_loss
                    out[1] = 1.0f - v1 * inv;      // reg_loss
                }
            }
        }
    }
}

extern "C" void kernel_launch(void* const* d_in, const int* in_sizes, int n_in,
                              void* d_out, int out_size, void* d_ws, size_t ws_size,
                              hipStream_t stream) {
    const float4* pred = (const float4*)d_in[0];
    const float*  gt   = (const float*)d_in[1];
    char* w = (char*)d_ws;
    unsigned* wflags   = (unsigned*)(w + O_WFLAGS);
    float*    partials = (float*)(w + O_PART);
    unsigned* done     = (unsigned*)(w + O_DONE);
    unsigned* fguard   = (unsigned*)(w + O_FGUARD);

    k_all<<<4 * NB, 1024, 0, stream>>>(pred, gt, wflags, partials, done, fguard, (float*)d_out);
}

// Round 3
// 69.280 us; speedup vs baseline: 1.0686x; 1.0009x over previous
//
#include <hip/hip_runtime.h>
#include <math.h>

// DotDetectionLoss on MI355X — SINGLE kernel node (finalize folded in via a
// poison-agnostic last-block pattern; only assumption: ws poison != MAGIC,
// same assumption the verified wflags trick already makes).
// pred: (16, 4096, 4) f32 = [cls, x, y, conf]; gt: (16, 1024, 3) f32 = [cls, x, y]
// out: float[2] = {obj_loss, reg_loss}
//
// Math: sigmoid(2.5-d) monotone in d => masked argmax(score) == argmin(d^2) among
// {class match, d2 <= 6.25}; score>=0.5 <=> d2 <= 6.25 (+1e-12 is sub-ulp).
// Spatial hash 64x64 cells (8px): r=2.5 disc spans <=2x2 cells (+0.01 window
// guard; superset safe — exact d2<=6.25 decides). Tie-break
// (d2<bd)||(d2==bd&&p<bp) == JAX argmax first-index (order-independent).
// Obj split: bce(x,1)=bce(x,0)-x => obj = [sum_p bce0(x_p) - sum_correct x_p]/BP.
// Class folded into SIGN BIT of stored x (inputs are >=0; fabsf is exact), so
// match AND reg phases are 100% LDS-resident: conf is deposited in sconf[] at
// fill time and the match reduce carries the winning SLOT, so the reg phase's
// former serial random-global pb[p] reloads (~900cyc HBM misses each — the
// poison fill evicts all caches every iteration) are now LDS reads.
// Match uses ALL 1024 threads: 4 threads/target, one per window cell, then a
// 2-step shfl_xor lexicographic (d2,p,slot) reduce within each 4-group.
//
// Finalize ordering (release/acquire, device-scope atomics):
//   publisher: partials exch -> __threadfence -> done exch -> s_waitcnt vmcnt(0)
//   (waitcnt guarantees OWN done exch is globally performed before this wave
//   samples the other 63 flags, so the globally-last publisher always sees
//   all-MAGIC => out is always written; fguard exch picks a unique finalizer.)

#define NB 16
#define NP 4096
#define NT 1024
#define MAGIC 0x5CA1AB1Eu

// ws layout (bytes): wflags u32[NB*NP] (256 KB) | partials f32[128] | done u32[64] | fguard u32
#define O_WFLAGS 0
#define O_PART   (NB * NP * 4)
#define O_DONE   (O_PART + 128 * 4)
#define O_FGUARD (O_DONE + 64 * 4)

__global__ __launch_bounds__(1024) void k_all(
    const float4* __restrict__ pred, const float* __restrict__ gt,
    unsigned* __restrict__ wflags, float* __restrict__ partials,
    unsigned* __restrict__ done, unsigned* __restrict__ fguard,
    float* __restrict__ out)
{
    const int bid = blockIdx.x;
    const int b = bid >> 2, q = bid & 3;      // 4 blocks per image
    const int tid = threadIdx.x, lane = tid & 63, wave = tid >> 6;

    __shared__ unsigned short scnt[4096];     // cell counts -> cursors -> ENDs
    __shared__ unsigned short sbins[4096];    // pred ids grouped by cell
    __shared__ float2 spxy[4096];             // binned pred (sign(cls)|x, y); first 12KB doubles as gt staging
    __shared__ float sconf[4096];             // binned pred conf (slot-indexed)
    __shared__ float2 sxy[NT];                // gt (sign(cls)|x, y)
    __shared__ unsigned short slist[256];     // owned correct preds (SLOT index)
    __shared__ unsigned scount;
    __shared__ unsigned wsum[16];
    __shared__ float pc[2];                   // obj partial, score partial

    const float4* pb = pred + (size_t)b * NP;
    const float*  gb = gt + (size_t)b * NT * 3;
    float* sraw = (float*)spxy;               // gt staging (12 KB of 32 KB; consumed before fill)

    // ---- init LDS + coalesced gt stage ----
    ((unsigned*)scnt)[tid] = 0u;
    ((unsigned*)scnt)[tid + 1024] = 0u;
    if (tid == 0) scount = 0u;
    if (tid < 2) pc[tid] = 0.0f;
    sraw[tid]        = gb[tid];
    sraw[tid + 1024] = gb[tid + 1024];
    sraw[tid + 2048] = gb[tid + 2048];
    __syncthreads();

    // ---- recombine gt (cls -> sign of x) ----
    {
        float c = sraw[3 * tid], x = sraw[3 * tid + 1], y = sraw[3 * tid + 2];
        sxy[tid] = make_float2(c != 0.0f ? -x : x, y);
    }

    // ---- count (packed u16 LDS atomics; halfwords <=4096, no carry) + BCE
    //      baseline on this block's owned quarter (k==q element, no extra load) ----
    float4 prv[4];
    int cellc[4];
    float lb = 0.0f;
    #pragma unroll
    for (int k = 0; k < 4; k++) {
        float4 pr = pb[tid + 1024 * k];
        prv[k] = pr;
        int cell = (int)(pr.y * 0.125f) + ((int)(pr.z * 0.125f) << 6);
        cellc[k] = cell;
        atomicAdd((unsigned*)scnt + (cell >> 1), (cell & 1) ? 0x10000u : 1u);
        if (k == q) {
            float x = pr.w;
            lb = fmaxf(x, 0.0f) + log1pf(expf(-fabsf(x)));   // bce(x, y=0)
        }
    }
    for (int off = 32; off; off >>= 1) lb += __shfl_down(lb, off, 64);
    if (lane == 0) atomicAdd(&pc[0], lb);
    __syncthreads();

    // ---- exclusive scan over 4096 cells (4 cells/thread, 16 waves) ----
    {
        int base = tid * 4;
        unsigned loc[4], s = 0;
        #pragma unroll
        for (int i = 0; i < 4; i++) { loc[i] = s; s += (unsigned)scnt[base + i]; }
        unsigned v = s;
        for (int off = 1; off < 64; off <<= 1) {
            unsigned o = __shfl_up(v, off, 64);
            if (lane >= off) v += o;
        }
        if (lane == 63) wsum[wave] = v;
        __syncthreads();
        unsigned wbase = 0;
        for (int w = 0; w < wave; w++) wbase += wsum[w];
        unsigned tbase = wbase + v - s;
        #pragma unroll
        for (int i = 0; i < 4; i++) scnt[base + i] = (unsigned short)(tbase + loc[i]);
    }
    __syncthreads();

    // ---- fill (cursor = packed atomic; post-fill scnt[c] == END of cell c);
    //      deposit (sign-encoded x, y) + conf so later phases never touch global ----
    #pragma unroll
    for (int k = 0; k < 4; k++) {
        int cell = cellc[k];
        unsigned old = atomicAdd((unsigned*)scnt + (cell >> 1), (cell & 1) ? 0x10000u : 1u);
        unsigned slot = (cell & 1) ? (old >> 16) : (old & 0xFFFFu);
        sbins[slot] = (unsigned short)(tid + 1024 * k);
        float4 pr = prv[k];
        spxy[slot]  = make_float2(pr.x != 0.0f ? -pr.y : pr.y, pr.z);
        sconf[slot] = pr.w;
    }
    __syncthreads();

    // ---- match: ALL 1024 threads, 4 threads per target (one per window cell) ----
    {
        const int t = q * 256 + (tid >> 2);
        const int j = tid & 3;
        float2 txy = sxy[t];
        const int tsign = __float_as_int(txy.x);
        const float tx = fabsf(txy.x), ty = txy.y;
        int x0 = (int)floorf((tx - 2.51f) * 0.125f); if (x0 < 0) x0 = 0;
        int x1 = (int)((tx + 2.51f) * 0.125f);       if (x1 > 63) x1 = 63;
        int y0 = (int)floorf((ty - 2.51f) * 0.125f); if (y0 < 0) y0 = 0;
        int y1 = (int)((ty + 2.51f) * 0.125f);       if (y1 > 63) y1 = 63;
        float bd = 3.0e38f; int bp = 0x7fffffff; int bs = 0;
        const int cx = x0 + (j & 1), cy = y0 + (j >> 1);
        if (cx <= x1 && cy <= y1) {
            const int c = cx + (cy << 6);
            unsigned s0 = c ? (unsigned)scnt[c - 1] : 0u;
            unsigned s1 = (unsigned)scnt[c];
            for (unsigned k = s0; k < s1; k++) {
                float2 pxy = spxy[k];
                if (((__float_as_int(pxy.x) ^ tsign) & 0x80000000) == 0) {   // class match
                    float dx = fabsf(pxy.x) - tx, dy = pxy.y - ty;           // fabsf exact: d2 bitwise-identical
                    float d2 = fmaf(dy, dy, dx * dx);
                    int p = sbins[k];
                    if (d2 < bd || (d2 == bd && p < bp)) { bd = d2; bp = p; bs = (int)k; }
                }
            }
        }
        #pragma unroll
        for (int m = 1; m <= 2; m <<= 1) {      // lexicographic (d2,p) reduce over the 4-group
            float od = __shfl_xor(bd, m, 64);
            int   op = __shfl_xor(bp, m, 64);
            int   os = __shfl_xor(bs, m, 64);
            if (od < bd || (od == bd && op < bp)) { bd = od; bp = op; bs = os; }
        }
        if (j == 0 && bd <= 6.25f) {
            // cross-block dedupe: first exchanger owns (poison != MAGIC), race-free
            unsigned old = atomicExch(&wflags[b * NP + bp], MAGIC);
            if (old != MAGIC)
                slist[atomicAdd(&scount, 1u)] = (unsigned short)bs;   // store SLOT
        }
    }
    __syncthreads();

    // ---- reg + obj correction: one wave per owned correct pred (16 waves);
    //      pred data from LDS (spxy/sconf via slot) — no random global loads ----
    {
        unsigned n = scount;
        float lc = 0.0f, ls = 0.0f;
        for (unsigned e = (unsigned)wave; e < n; e += 16) {
            int sl = slist[e];
            float2 pxys = spxy[sl];
            float px = fabsf(pxys.x), py = pxys.y;
            float md = 1.0e30f;
            #pragma unroll 4
            for (int t = lane; t < NT; t += 64) {
                float2 xy = sxy[t];
                float dx = px - fabsf(xy.x), dy = py - xy.y;
                md = fminf(md, fmaf(dy, dy, dx * dx));
            }
            for (int off = 32; off; off >>= 1)
                md = fminf(md, __shfl_down(md, off, 64));
            if (lane == 0) {
                float dd = sqrtf(md + 1e-12f);
                ls += 1.0f / (1.0f + expf(dd - 2.5f));
                lc += sconf[sl];              // bce(x,1) = bce(x,0) - x
            }
        }
        if (lane == 0 && (lc != 0.0f || ls != 0.0f)) {
            atomicAdd(&pc[0], -lc);           // obj partial -= correction
            atomicAdd(&pc[1], ls);
        }
    }
    __syncthreads();

    // ---- publish (device-scope atomics: coherent across XCD L2s) + last-block
    //      finalize. Release: partials -> fence -> done[bid]=MAGIC. The
    //      s_waitcnt vmcnt(0) below is wave-wide: it guarantees lane 0's done
    //      exch is globally performed BEFORE any lane of wave 0 issues its
    //      flag read, so the globally-last publisher must observe all 64
    //      flags == MAGIC (own flag substituted locally) => out always
    //      written. fguard exch (poison != MAGIC) picks a unique finalizer;
    //      its returned value is consumed, so the wave waits before reading
    //      partials (plus acquire threadfence). Summation order replicates
    //      the old k_fin exactly => bitwise-same out. ----
    if (tid == 0) {
        atomicExch(&partials[bid], pc[0]);         // obj partial
        atomicExch(&partials[64 + bid], pc[1]);    // score partial
        __threadfence();
        atomicExch(&done[bid], MAGIC);
    }
    if (wave == 0) {
        asm volatile("s_waitcnt vmcnt(0)" ::: "memory");   // own exch performed
        unsigned f = (lane == bid) ? MAGIC : atomicAdd(&done[lane], 0u);
        if (__ballot(f == MAGIC) == ~0ull) {
            int win = 0;
            if (lane == 0) win = (atomicExch(fguard, MAGIC) != MAGIC) ? 1 : 0;
            if (__shfl(win, 0, 64)) {
                __threadfence();
                // identical summation order to the old k_fin => bitwise-same out
                float v0 = atomicAdd(&partials[lane], 0.0f);
                for (int off = 32; off; off >>= 1) v0 += __shfl_down(v0, off, 64);
                float v1 = atomicAdd(&partials[64 + lane], 0.0f);
                for (int off = 32; off; off >>= 1) v1 += __shfl_down(v1, off, 64);
                if (lane == 0) {
                    const float inv = 1.0f / (float)(NB * NP);
                    out[0] = v0 * inv;             // obj_loss
                    out[1] = 1.0f - v1 * inv;      // reg_loss
                }
            }
        }
    }
}

extern "C" void kernel_launch(void* const* d_in, const int* in_sizes, int n_in,
                              void* d_out, int out_size, void* d_ws, size_t ws_size,
                              hipStream_t stream) {
    const float4* pred = (const float4*)d_in[0];
    const float*  gt   = (const float*)d_in[1];
    char* w = (char*)d_ws;
    unsigned* wflags   = (unsigned*)(w + O_WFLAGS);
    float*    partials = (float*)(w + O_PART);
    unsigned* done     = (unsigned*)(w + O_DONE);
    unsigned* fguard   = (unsigned*)(w + O_FGUARD);

    k_all<<<4 * NB, 1024, 0, stream>>>(pred, gt, wflags, partials, done, fguard, (float*)d_out);
}